// Round 15
// baseline (88.051 us; speedup 1.0000x reference)
//
#include <hip/hip_runtime.h>
#include <math.h>

#define RED_BLOCKS 256
#define NT 512             // k_h threads
#define AT 1024            // k_accum threads
#define CCH 10000          // nodes per chunk; both dirs = 80000 B -> 2 blocks/CU with margin
#define ORD_OFF 0x007fffffu  // f2ord(-inf); shifted so 0 == "-inf"/empty

// Monotone order-preserving float->uint mapping, shifted so 0 means -inf.
__device__ __forceinline__ unsigned f2ord(float f) {
    unsigned u = __float_as_uint(f);
    u = (u & 0x80000000u) ? ~u : (u | 0x80000000u);
    return u - ORD_OFF;
}
__device__ __forceinline__ float ord2f(unsigned uo) {
    unsigned u = uo + ORD_OFF;
    unsigned v = (u & 0x80000000u) ? (u & 0x7fffffffu) : ~u;
    return __uint_as_float(v);
}

__device__ __forceinline__ void h_row_body(const float* __restrict__ loss,
                                           const float* __restrict__ Ws,
                                           float* __restrict__ h,
                                           unsigned* __restrict__ ordArr,
                                           int n, int blk) {
    int sub = threadIdx.x & 15, r = threadIdx.x >> 4;   // 32 rows per 512-thread block
    int row = blk * (NT / 16) + r;
    if (row >= n) return;
    const float4* f4 = (const float4*)(loss + (size_t)row * 200);
    const float4* W4 = (const float4*)Ws;
    float4 a, w;
    float acc = 0.0f;
    a = f4[sub];      w = W4[sub];      acc += a.x*w.x + a.y*w.y + a.z*w.z + a.w*w.w;
    a = f4[sub + 16]; w = W4[sub + 16]; acc += a.x*w.x + a.y*w.y + a.z*w.z + a.w*w.w;
    a = f4[sub + 32]; w = W4[sub + 32]; acc += a.x*w.x + a.y*w.y + a.z*w.z + a.w*w.w;
    if (sub < 2) { a = f4[48 + sub]; w = W4[48 + sub]; acc += a.x*w.x + a.y*w.y + a.z*w.z + a.w*w.w; }
    #pragma unroll
    for (int off = 8; off > 0; off >>= 1) acc += __shfl_down(acc, off, 16);
    if (sub == 0) { h[row] = acc; ordArr[row] = f2ord(acc); }
}

__global__ void __launch_bounds__(NT) k_h(const float* __restrict__ loss,
                                          const float* __restrict__ Ws,
                                          float* __restrict__ h,
                                          unsigned* __restrict__ ordArr, int n) {
    h_row_body(loss, Ws, h, ordArr, n, blockIdx.x);
}

// Scatter-free segment-max. chunk = 10000 nodes, both dirs = 80000 B LDS ->
// TRUE 2 blocks/CU (round-14 used exactly 160 KiB and lost co-residency:
// occupancy 75%, L3 edge-reuse broken, FETCH 4x). Grid 510 <= 512 resident
// slots so all same-slice chunk groups run concurrently and L3 serves the
// nch x edge re-read. Non-returning LDS atomics only; exact, order-free ->
// bit-deterministic.
__global__ void __launch_bounds__(AT, 8) k_accum(
        const int* __restrict__ src, const int* __restrict__ dst,
        const unsigned* __restrict__ ordArr, unsigned* __restrict__ partials,
        int ne, int nch, int split, int epb) {
    __shared__ unsigned preL[CCH];
    __shared__ unsigned sucL[CCH];
    int c = blockIdx.x / split, sub = blockIdx.x - c * split;
    for (int t = threadIdx.x; t < CCH; t += AT) { preL[t] = 0u; sucL[t] = 0u; }
    __syncthreads();
    const unsigned clo = (unsigned)c * CCH;
    int lo = sub * epb, hi = min(lo + epb, ne);
    for (int i = lo + (int)threadIdx.x * 4; i < hi; i += AT * 4) {
        if (i + 3 < hi) {
            int4 a = *(const int4*)(src + i);
            int4 b = *(const int4*)(dst + i);
            unsigned dl, sl;
            if (a.x != b.x) {
                dl = (unsigned)b.x - clo;
                if (dl < CCH) atomicMax(&preL[dl], ordArr[a.x]);
                sl = (unsigned)a.x - clo;
                if (sl < CCH) atomicMax(&sucL[sl], ordArr[b.x]);
            }
            if (a.y != b.y) {
                dl = (unsigned)b.y - clo;
                if (dl < CCH) atomicMax(&preL[dl], ordArr[a.y]);
                sl = (unsigned)a.y - clo;
                if (sl < CCH) atomicMax(&sucL[sl], ordArr[b.y]);
            }
            if (a.z != b.z) {
                dl = (unsigned)b.z - clo;
                if (dl < CCH) atomicMax(&preL[dl], ordArr[a.z]);
                sl = (unsigned)a.z - clo;
                if (sl < CCH) atomicMax(&sucL[sl], ordArr[b.z]);
            }
            if (a.w != b.w) {
                dl = (unsigned)b.w - clo;
                if (dl < CCH) atomicMax(&preL[dl], ordArr[a.w]);
                sl = (unsigned)a.w - clo;
                if (sl < CCH) atomicMax(&sucL[sl], ordArr[b.w]);
            }
        } else {
            for (int j = i; j < hi && j < i + 4; ++j) {
                int s = src[j], d = dst[j];
                if (s != d) {
                    unsigned dl = (unsigned)d - clo;
                    if (dl < CCH) atomicMax(&preL[dl], ordArr[s]);
                    unsigned sl = (unsigned)s - clo;
                    if (sl < CCH) atomicMax(&sucL[sl], ordArr[d]);
                }
            }
        }
    }
    __syncthreads();
    size_t pb = ((size_t)c * split + sub) * CCH;
    size_t sucOff = (size_t)nch * split * CCH;
    for (int t = threadIdx.x; t < CCH; t += AT) {
        partials[pb + t] = preL[t];
        partials[sucOff + pb + t] = sucL[t];
    }
}

// ---- Fallback: device-scope filtered atomics (pre at [0], suc at [1<<17]) ----
__global__ void k_edges_dev(const int* __restrict__ src, const int* __restrict__ dst,
                            const float* __restrict__ h, unsigned* __restrict__ partials, int ne) {
    int e = blockIdx.x * blockDim.x + threadIdx.x;
    if (e >= ne) return;
    int s = src[e], d = dst[e];
    if (s == d) return;
    unsigned hs = f2ord(h[s]);
    unsigned hd = f2ord(h[d]);
    unsigned* slot0 = &partials[d];
    unsigned* slot1 = &partials[(1 << 17) + s];
    if (*slot0 < hs) atomicMax(slot0, hs);
    if (*slot1 < hd) atomicMax(slot1, hd);
}

// Fold split partials per direction; logit = h + w0*pre + w1*suc (0 -> 0.0);
// block-partial max (fixed RED_BLOCKS grid).
__global__ void k_logit_max(const float* __restrict__ h, const unsigned* __restrict__ partials,
                            const float* __restrict__ Wg, float* __restrict__ logit,
                            float* __restrict__ maxPart, int n, int nch, int split) {
    __shared__ float sm[256];
    float w0 = Wg[0], w1 = Wg[1];
    size_t sucOff = (size_t)nch * split * CCH;
    float m = -INFINITY;
    for (int i = blockIdx.x * 256 + threadIdx.x; i < n; i += 256 * RED_BLOCKS) {
        int c = i / CCH, loc = i - c * CCH;
        const unsigned* pp = partials + ((size_t)c * split) * CCH + loc;
        const unsigned* sp = pp + sucOff;
        unsigned p = 0, s = 0;
        #pragma unroll 4
        for (int k = 0; k < split; ++k) {
            p = max(p, pp[(size_t)k * CCH]);
            s = max(s, sp[(size_t)k * CCH]);
        }
        float pf = p ? ord2f(p) : 0.0f;
        float sf = s ? ord2f(s) : 0.0f;
        float l = h[i] + w0 * pf + w1 * sf;
        logit[i] = l;
        m = fmaxf(m, l);
    }
    sm[threadIdx.x] = m;
    __syncthreads();
    for (int off = 128; off > 0; off >>= 1) {
        if (threadIdx.x < off) sm[threadIdx.x] = fmaxf(sm[threadIdx.x], sm[threadIdx.x + off]);
        __syncthreads();
    }
    if (threadIdx.x == 0) maxPart[blockIdx.x] = sm[0];
}

// Fallback fold (flat pre/suc arrays).
__global__ void k_logit_max_dev(const float* __restrict__ h, const unsigned* __restrict__ partials,
                                const float* __restrict__ Wg, float* __restrict__ logit,
                                float* __restrict__ maxPart, int n) {
    __shared__ float sm[256];
    float w0 = Wg[0], w1 = Wg[1];
    float m = -INFINITY;
    for (int i = blockIdx.x * 256 + threadIdx.x; i < n; i += 256 * RED_BLOCKS) {
        unsigned p = partials[i], s = partials[(1 << 17) + i];
        float pf = p ? ord2f(p) : 0.0f;
        float sf = s ? ord2f(s) : 0.0f;
        float l = h[i] + w0 * pf + w1 * sf;
        logit[i] = l;
        m = fmaxf(m, l);
    }
    sm[threadIdx.x] = m;
    __syncthreads();
    for (int off = 128; off > 0; off >>= 1) {
        if (threadIdx.x < off) sm[threadIdx.x] = fmaxf(sm[threadIdx.x], sm[threadIdx.x + off]);
        __syncthreads();
    }
    if (threadIdx.x == 0) maxPart[blockIdx.x] = sm[0];
}

__global__ void k_exp_sum(const float* __restrict__ logit, const float* __restrict__ maxPart,
                          float* __restrict__ out, float* __restrict__ sumPart, int n) {
    __shared__ float sm[256];
    sm[threadIdx.x] = maxPart[threadIdx.x];
    __syncthreads();
    for (int off = 128; off > 0; off >>= 1) {
        if (threadIdx.x < off) sm[threadIdx.x] = fmaxf(sm[threadIdx.x], sm[threadIdx.x + off]);
        __syncthreads();
    }
    float gmax = sm[0];
    __syncthreads();
    float acc = 0.0f;
    for (int i = blockIdx.x * 256 + threadIdx.x; i < n; i += 256 * RED_BLOCKS) {
        float e = expf(logit[i] - gmax);
        out[i] = e;
        acc += e;
    }
    sm[threadIdx.x] = acc;
    __syncthreads();
    for (int off = 128; off > 0; off >>= 1) {
        if (threadIdx.x < off) sm[threadIdx.x] += sm[threadIdx.x + off];
        __syncthreads();
    }
    if (threadIdx.x == 0) sumPart[blockIdx.x] = sm[0];
}

__global__ void k_norm(const float* __restrict__ sumPart, float* __restrict__ out, int n) {
    __shared__ float sm[256];
    sm[threadIdx.x] = sumPart[threadIdx.x];
    __syncthreads();
    for (int off = 128; off > 0; off >>= 1) {
        if (threadIdx.x < off) sm[threadIdx.x] += sm[threadIdx.x + off];
        __syncthreads();
    }
    float inv = 1.0f / sm[0];
    for (int i = blockIdx.x * 256 + threadIdx.x; i < n; i += 256 * RED_BLOCKS) out[i] *= inv;
}

extern "C" void kernel_launch(void* const* d_in, const int* in_sizes, int n_in,
                              void* d_out, int out_size, void* d_ws, size_t ws_size,
                              hipStream_t stream) {
    const float* loss = (const float*)d_in[0];   // [N, 200]
    const float* Ws   = (const float*)d_in[1];   // [1, 200]
    const float* Wg   = (const float*)d_in[2];   // [1, 2]
    const int* esrc   = (const int*)d_in[3];     // [E]
    const int* edst   = (const int*)d_in[4];     // [E]
    float* out = (float*)d_out;                  // [N]

    const int n  = in_sizes[0] / 200;
    const int ne = in_sizes[3];
    const int Gh = (n + (NT / 16) - 1) / (NT / 16);

    const int nch = (n + CCH - 1) / CCH;                 // node chunks (10 @ n=100K)
    int split = 510 / nch; if (split < 1) split = 1;     // grid <= 510: all co-resident at 2/CU
    const int epb = (((ne + split - 1) / split) + 3) & ~3;

    // ws layout (32-bit words):
    // h[n] | logit[n] | ordArr[n] | maxPart | sumPart | partials[2*nch*split*CCH]
    float*    h        = (float*)d_ws;
    float*    logit    = h + n;
    unsigned* ordArr   = (unsigned*)(logit + n);
    float*    maxPart  = (float*)(ordArr + n);
    float*    sumPart  = maxPart + RED_BLOCKS;
    unsigned* partials = (unsigned*)(sumPart + RED_BLOCKS);
    size_t part_w = (size_t)2 * nch * split * CCH;
    size_t need = ((size_t)3 * n + 2 * RED_BLOCKS + part_w) * 4;

    k_h<<<Gh, NT, 0, stream>>>(loss, Ws, h, ordArr, n);

    if (need <= ws_size) {
        k_accum<<<nch * split, AT, 0, stream>>>(esrc, edst, ordArr, partials, ne, nch, split, epb);
        k_logit_max<<<RED_BLOCKS, 256, 0, stream>>>(h, partials, Wg, logit, maxPart, n, nch, split);
    } else {
        hipMemsetAsync(partials, 0, (size_t)2 * (1 << 17) * 4, stream);
        k_edges_dev<<<(ne + 255) / 256, 256, 0, stream>>>(esrc, edst, h, partials, ne);
        k_logit_max_dev<<<RED_BLOCKS, 256, 0, stream>>>(h, partials, Wg, logit, maxPart, n);
    }

    k_exp_sum<<<RED_BLOCKS, 256, 0, stream>>>(logit, maxPart, out, sumPart, n);
    k_norm<<<RED_BLOCKS, 256, 0, stream>>>(sumPart, out, n);
}

// Round 16
// 78.939 us; speedup vs baseline: 1.1154x; 1.1154x over previous
//
#include <hip/hip_runtime.h>
#include <math.h>

#define RED_BLOCKS 256
#define NT 512             // k_h threads
#define AT 1024            // k_accum threads (16 waves, 1 block/CU)
#define CCH 16384          // nodes per chunk; both dirs = 128 KB LDS
#define ORD_OFF 0x007fffffu  // f2ord(-inf); shifted so 0 == "-inf"/empty

// Monotone order-preserving float->uint mapping, shifted so 0 means -inf.
__device__ __forceinline__ unsigned f2ord(float f) {
    unsigned u = __float_as_uint(f);
    u = (u & 0x80000000u) ? ~u : (u | 0x80000000u);
    return u - ORD_OFF;
}
__device__ __forceinline__ float ord2f(unsigned uo) {
    unsigned u = uo + ORD_OFF;
    unsigned v = (u & 0x80000000u) ? (u & 0x7fffffffu) : ~u;
    return __uint_as_float(v);
}

__device__ __forceinline__ void h_row_body(const float* __restrict__ loss,
                                           const float* __restrict__ Ws,
                                           float* __restrict__ h,
                                           unsigned* __restrict__ ordArr,
                                           int n, int blk) {
    int sub = threadIdx.x & 15, r = threadIdx.x >> 4;   // 32 rows per 512-thread block
    int row = blk * (NT / 16) + r;
    if (row >= n) return;
    const float4* f4 = (const float4*)(loss + (size_t)row * 200);
    const float4* W4 = (const float4*)Ws;
    float4 a, w;
    float acc = 0.0f;
    a = f4[sub];      w = W4[sub];      acc += a.x*w.x + a.y*w.y + a.z*w.z + a.w*w.w;
    a = f4[sub + 16]; w = W4[sub + 16]; acc += a.x*w.x + a.y*w.y + a.z*w.z + a.w*w.w;
    a = f4[sub + 32]; w = W4[sub + 32]; acc += a.x*w.x + a.y*w.y + a.z*w.z + a.w*w.w;
    if (sub < 2) { a = f4[48 + sub]; w = W4[48 + sub]; acc += a.x*w.x + a.y*w.y + a.z*w.z + a.w*w.w; }
    #pragma unroll
    for (int off = 8; off > 0; off >>= 1) acc += __shfl_down(acc, off, 16);
    if (sub == 0) { h[row] = acc; ordArr[row] = f2ord(acc); }
}

__global__ void __launch_bounds__(NT) k_h(const float* __restrict__ loss,
                                          const float* __restrict__ Ws,
                                          float* __restrict__ h,
                                          unsigned* __restrict__ ordArr, int n) {
    h_row_body(loss, Ws, h, ordArr, n, blockIdx.x);
}

// Scatter-free segment-max, ILP-restructured. Rounds 13-15 all hit 58 us
// with VGPR=12: ~2 loads in flight/thread -> per-wave latency chain was the
// bound, independent of pass count / occupancy / bytes. Fix: 16 edges per
// thread per iteration, ALL 8 int4 loads issued before any use (8 in
// flight/thread; ~128 KB/CU at 16 waves), launch_bounds(1024,4) -> 128 VGPR
// so loads live in registers. Non-returning LDS atomics; exact, order-free
// -> bit-deterministic.
__global__ void __launch_bounds__(AT, 4) k_accum(
        const int* __restrict__ src, const int* __restrict__ dst,
        const unsigned* __restrict__ ordArr, unsigned* __restrict__ partials,
        int ne, int nch, int split, int epb) {
    __shared__ unsigned preL[CCH];
    __shared__ unsigned sucL[CCH];
    int c = blockIdx.x / split, sub = blockIdx.x - c * split;
    for (int t = threadIdx.x; t < CCH; t += AT) { preL[t] = 0u; sucL[t] = 0u; }
    __syncthreads();
    const unsigned clo = (unsigned)c * CCH;
    int lo = sub * epb, hi = min(sub * epb + epb, ne);

    int i = lo + (int)threadIdx.x * 16;
    for (; i + 15 < hi; i += AT * 16) {
        int4 s0 = *(const int4*)(src + i);
        int4 s1 = *(const int4*)(src + i + 4);
        int4 s2 = *(const int4*)(src + i + 8);
        int4 s3 = *(const int4*)(src + i + 12);
        int4 d0 = *(const int4*)(dst + i);
        int4 d1 = *(const int4*)(dst + i + 4);
        int4 d2 = *(const int4*)(dst + i + 8);
        int4 d3 = *(const int4*)(dst + i + 12);
        int ss[16] = { s0.x, s0.y, s0.z, s0.w, s1.x, s1.y, s1.z, s1.w,
                       s2.x, s2.y, s2.z, s2.w, s3.x, s3.y, s3.z, s3.w };
        int dd[16] = { d0.x, d0.y, d0.z, d0.w, d1.x, d1.y, d1.z, d1.w,
                       d2.x, d2.y, d2.z, d2.w, d3.x, d3.y, d3.z, d3.w };
        #pragma unroll
        for (int u = 0; u < 16; ++u) {
            int s = ss[u], d = dd[u];
            if (s != d) {
                unsigned dl = (unsigned)d - clo;
                if (dl < CCH) atomicMax(&preL[dl], ordArr[s]);
                unsigned sl = (unsigned)s - clo;
                if (sl < CCH) atomicMax(&sucL[sl], ordArr[d]);
            }
        }
    }
    for (int j = i; j < hi; ++j) {   // tail (last partial 16-pack of this thread)
        if (j >= lo) {
            int s = src[j], d = dst[j];
            if (s != d) {
                unsigned dl = (unsigned)d - clo;
                if (dl < CCH) atomicMax(&preL[dl], ordArr[s]);
                unsigned sl = (unsigned)s - clo;
                if (sl < CCH) atomicMax(&sucL[sl], ordArr[d]);
            }
        }
    }
    __syncthreads();
    size_t pb = ((size_t)c * split + sub) * CCH;
    size_t sucOff = (size_t)nch * split * CCH;
    for (int t = threadIdx.x; t < CCH; t += AT) {
        partials[pb + t] = preL[t];
        partials[sucOff + pb + t] = sucL[t];
    }
}

// ---- Fallback: device-scope filtered atomics (pre at [0], suc at [1<<17]) ----
__global__ void k_edges_dev(const int* __restrict__ src, const int* __restrict__ dst,
                            const float* __restrict__ h, unsigned* __restrict__ partials, int ne) {
    int e = blockIdx.x * blockDim.x + threadIdx.x;
    if (e >= ne) return;
    int s = src[e], d = dst[e];
    if (s == d) return;
    unsigned hs = f2ord(h[s]);
    unsigned hd = f2ord(h[d]);
    unsigned* slot0 = &partials[d];
    unsigned* slot1 = &partials[(1 << 17) + s];
    if (*slot0 < hs) atomicMax(slot0, hs);
    if (*slot1 < hd) atomicMax(slot1, hd);
}

// Fold split partials per direction; logit = h + w0*pre + w1*suc (0 -> 0.0);
// block-partial max (fixed RED_BLOCKS grid).
__global__ void k_logit_max(const float* __restrict__ h, const unsigned* __restrict__ partials,
                            const float* __restrict__ Wg, float* __restrict__ logit,
                            float* __restrict__ maxPart, int n, int nch, int split) {
    __shared__ float sm[256];
    float w0 = Wg[0], w1 = Wg[1];
    size_t sucOff = (size_t)nch * split * CCH;
    float m = -INFINITY;
    for (int i = blockIdx.x * 256 + threadIdx.x; i < n; i += 256 * RED_BLOCKS) {
        int c = i / CCH, loc = i - c * CCH;
        const unsigned* pp = partials + ((size_t)c * split) * CCH + loc;
        const unsigned* sp = pp + sucOff;
        unsigned p = 0, s = 0;
        #pragma unroll 4
        for (int k = 0; k < split; ++k) {
            p = max(p, pp[(size_t)k * CCH]);
            s = max(s, sp[(size_t)k * CCH]);
        }
        float pf = p ? ord2f(p) : 0.0f;
        float sf = s ? ord2f(s) : 0.0f;
        float l = h[i] + w0 * pf + w1 * sf;
        logit[i] = l;
        m = fmaxf(m, l);
    }
    sm[threadIdx.x] = m;
    __syncthreads();
    for (int off = 128; off > 0; off >>= 1) {
        if (threadIdx.x < off) sm[threadIdx.x] = fmaxf(sm[threadIdx.x], sm[threadIdx.x + off]);
        __syncthreads();
    }
    if (threadIdx.x == 0) maxPart[blockIdx.x] = sm[0];
}

// Fallback fold (flat pre/suc arrays).
__global__ void k_logit_max_dev(const float* __restrict__ h, const unsigned* __restrict__ partials,
                                const float* __restrict__ Wg, float* __restrict__ logit,
                                float* __restrict__ maxPart, int n) {
    __shared__ float sm[256];
    float w0 = Wg[0], w1 = Wg[1];
    float m = -INFINITY;
    for (int i = blockIdx.x * 256 + threadIdx.x; i < n; i += 256 * RED_BLOCKS) {
        unsigned p = partials[i], s = partials[(1 << 17) + i];
        float pf = p ? ord2f(p) : 0.0f;
        float sf = s ? ord2f(s) : 0.0f;
        float l = h[i] + w0 * pf + w1 * sf;
        logit[i] = l;
        m = fmaxf(m, l);
    }
    sm[threadIdx.x] = m;
    __syncthreads();
    for (int off = 128; off > 0; off >>= 1) {
        if (threadIdx.x < off) sm[threadIdx.x] = fmaxf(sm[threadIdx.x], sm[threadIdx.x + off]);
        __syncthreads();
    }
    if (threadIdx.x == 0) maxPart[blockIdx.x] = sm[0];
}

__global__ void k_exp_sum(const float* __restrict__ logit, const float* __restrict__ maxPart,
                          float* __restrict__ out, float* __restrict__ sumPart, int n) {
    __shared__ float sm[256];
    sm[threadIdx.x] = maxPart[threadIdx.x];
    __syncthreads();
    for (int off = 128; off > 0; off >>= 1) {
        if (threadIdx.x < off) sm[threadIdx.x] = fmaxf(sm[threadIdx.x], sm[threadIdx.x + off]);
        __syncthreads();
    }
    float gmax = sm[0];
    __syncthreads();
    float acc = 0.0f;
    for (int i = blockIdx.x * 256 + threadIdx.x; i < n; i += 256 * RED_BLOCKS) {
        float e = expf(logit[i] - gmax);
        out[i] = e;
        acc += e;
    }
    sm[threadIdx.x] = acc;
    __syncthreads();
    for (int off = 128; off > 0; off >>= 1) {
        if (threadIdx.x < off) sm[threadIdx.x] += sm[threadIdx.x + off];
        __syncthreads();
    }
    if (threadIdx.x == 0) sumPart[blockIdx.x] = sm[0];
}

__global__ void k_norm(const float* __restrict__ sumPart, float* __restrict__ out, int n) {
    __shared__ float sm[256];
    sm[threadIdx.x] = sumPart[threadIdx.x];
    __syncthreads();
    for (int off = 128; off > 0; off >>= 1) {
        if (threadIdx.x < off) sm[threadIdx.x] += sm[threadIdx.x + off];
        __syncthreads();
    }
    float inv = 1.0f / sm[0];
    for (int i = blockIdx.x * 256 + threadIdx.x; i < n; i += 256 * RED_BLOCKS) out[i] *= inv;
}

extern "C" void kernel_launch(void* const* d_in, const int* in_sizes, int n_in,
                              void* d_out, int out_size, void* d_ws, size_t ws_size,
                              hipStream_t stream) {
    const float* loss = (const float*)d_in[0];   // [N, 200]
    const float* Ws   = (const float*)d_in[1];   // [1, 200]
    const float* Wg   = (const float*)d_in[2];   // [1, 2]
    const int* esrc   = (const int*)d_in[3];     // [E]
    const int* edst   = (const int*)d_in[4];     // [E]
    float* out = (float*)d_out;                  // [N]

    const int n  = in_sizes[0] / 200;
    const int ne = in_sizes[3];
    const int Gh = (n + (NT / 16) - 1) / (NT / 16);

    const int nch = (n + CCH - 1) / CCH;                 // node chunks (7 @ n=100K)
    int split = 256 / nch; if (split < 1) split = 1;     // 1 block/CU, full residency
    const int epb = (((ne + split - 1) / split) + 15) & ~15;  // 16-aligned

    // ws layout (32-bit words):
    // h[n] | logit[n] | ordArr[n] | maxPart | sumPart | partials[2*nch*split*CCH]
    float*    h        = (float*)d_ws;
    float*    logit    = h + n;
    unsigned* ordArr   = (unsigned*)(logit + n);
    float*    maxPart  = (float*)(ordArr + n);
    float*    sumPart  = maxPart + RED_BLOCKS;
    unsigned* partials = (unsigned*)(sumPart + RED_BLOCKS);
    size_t part_w = (size_t)2 * nch * split * CCH;
    size_t need = ((size_t)3 * n + 2 * RED_BLOCKS + part_w) * 4;

    k_h<<<Gh, NT, 0, stream>>>(loss, Ws, h, ordArr, n);

    if (need <= ws_size) {
        k_accum<<<nch * split, AT, 0, stream>>>(esrc, edst, ordArr, partials, ne, nch, split, epb);
        k_logit_max<<<RED_BLOCKS, 256, 0, stream>>>(h, partials, Wg, logit, maxPart, n, nch, split);
    } else {
        hipMemsetAsync(partials, 0, (size_t)2 * (1 << 17) * 4, stream);
        k_edges_dev<<<(ne + 255) / 256, 256, 0, stream>>>(esrc, edst, h, partials, ne);
        k_logit_max_dev<<<RED_BLOCKS, 256, 0, stream>>>(h, partials, Wg, logit, maxPart, n);
    }

    k_exp_sum<<<RED_BLOCKS, 256, 0, stream>>>(logit, maxPart, out, sumPart, n);
    k_norm<<<RED_BLOCKS, 256, 0, stream>>>(sumPart, out, n);
}

// Round 17
// 74.258 us; speedup vs baseline: 1.1857x; 1.0630x over previous
//
#include <hip/hip_runtime.h>
#include <math.h>

#define RED_BLOCKS 256
#define NT 512             // k_h threads
#define AT 1024            // k_accum threads (16 waves, 1 block/CU)
#define CCH 16384          // nodes per chunk; both dirs = 128 KB LDS
#define ORD_OFF 0x007fffffu  // f2ord(-inf); shifted so 0 == "-inf"/empty

// Monotone order-preserving float->uint mapping, shifted so 0 means -inf.
__device__ __forceinline__ unsigned f2ord(float f) {
    unsigned u = __float_as_uint(f);
    u = (u & 0x80000000u) ? ~u : (u | 0x80000000u);
    return u - ORD_OFF;
}
__device__ __forceinline__ float ord2f(unsigned uo) {
    unsigned u = uo + ORD_OFF;
    unsigned v = (u & 0x80000000u) ? (u & 0x7fffffffu) : ~u;
    return __uint_as_float(v);
}

__device__ __forceinline__ void h_row_body(const float* __restrict__ loss,
                                           const float* __restrict__ Ws,
                                           float* __restrict__ h,
                                           unsigned* __restrict__ ordArr,
                                           int n, int blk) {
    int sub = threadIdx.x & 15, r = threadIdx.x >> 4;   // 32 rows per 512-thread block
    int row = blk * (NT / 16) + r;
    if (row >= n) return;
    const float4* f4 = (const float4*)(loss + (size_t)row * 200);
    const float4* W4 = (const float4*)Ws;
    float4 a, w;
    float acc = 0.0f;
    a = f4[sub];      w = W4[sub];      acc += a.x*w.x + a.y*w.y + a.z*w.z + a.w*w.w;
    a = f4[sub + 16]; w = W4[sub + 16]; acc += a.x*w.x + a.y*w.y + a.z*w.z + a.w*w.w;
    a = f4[sub + 32]; w = W4[sub + 32]; acc += a.x*w.x + a.y*w.y + a.z*w.z + a.w*w.w;
    if (sub < 2) { a = f4[48 + sub]; w = W4[48 + sub]; acc += a.x*w.x + a.y*w.y + a.z*w.z + a.w*w.w; }
    #pragma unroll
    for (int off = 8; off > 0; off >>= 1) acc += __shfl_down(acc, off, 16);
    if (sub == 0) { h[row] = acc; ordArr[row] = f2ord(acc); }
}

__global__ void __launch_bounds__(NT) k_h(const float* __restrict__ loss,
                                          const float* __restrict__ Ws,
                                          float* __restrict__ h,
                                          unsigned* __restrict__ ordArr, int n) {
    h_row_body(loss, Ws, h, ordArr, n, blockIdx.x);
}

// Scatter-free segment-max, gather-batched. Round-16 lesson: edge loads were
// batched but the ordArr gather stayed INSIDE the conditional atomic, so each
// triggering edge serialized branch -> gather -> vmcnt(0) -> atomic (~47
// cyc/visit, VALUBusy 14%). Fix: 3 phases per 16-edge pack -- (1) 8 int4
// edge loads in flight, (2) ALL needed gathers issued as exec-masked
// independent loads into registers (up to 32 in flight/thread), (3) the LDS
// atomics. launch_bounds(1024,4) -> 128 VGPR budget for gather results.
// Non-returning LDS atomics; exact, order-free -> bit-deterministic.
__global__ void __launch_bounds__(AT, 4) k_accum(
        const int* __restrict__ src, const int* __restrict__ dst,
        const unsigned* __restrict__ ordArr, unsigned* __restrict__ partials,
        int ne, int nch, int split, int epb) {
    __shared__ unsigned preL[CCH];
    __shared__ unsigned sucL[CCH];
    int c = blockIdx.x / split, sub = blockIdx.x - c * split;
    for (int t = threadIdx.x; t < CCH; t += AT) { preL[t] = 0u; sucL[t] = 0u; }
    __syncthreads();
    const unsigned clo = (unsigned)c * CCH;
    int lo = sub * epb, hi = min(sub * epb + epb, ne);

    int i = lo + (int)threadIdx.x * 16;
    for (; i + 15 < hi; i += AT * 16) {
        // phase 1: 8 independent edge loads
        int4 s0 = *(const int4*)(src + i);
        int4 s1 = *(const int4*)(src + i + 4);
        int4 s2 = *(const int4*)(src + i + 8);
        int4 s3 = *(const int4*)(src + i + 12);
        int4 d0 = *(const int4*)(dst + i);
        int4 d1 = *(const int4*)(dst + i + 4);
        int4 d2 = *(const int4*)(dst + i + 8);
        int4 d3 = *(const int4*)(dst + i + 12);
        int ss[16] = { s0.x, s0.y, s0.z, s0.w, s1.x, s1.y, s1.z, s1.w,
                       s2.x, s2.y, s2.z, s2.w, s3.x, s3.y, s3.z, s3.w };
        int dd[16] = { d0.x, d0.y, d0.z, d0.w, d1.x, d1.y, d1.z, d1.w,
                       d2.x, d2.y, d2.z, d2.w, d3.x, d3.y, d3.z, d3.w };
        // phase 2: membership + batched exec-masked gathers (independent)
        unsigned dl[16], sl[16], gp[16], gs[16];
        #pragma unroll
        for (int u = 0; u < 16; ++u) {
            bool same = (ss[u] == dd[u]);
            dl[u] = same ? ~0u : (unsigned)dd[u] - clo;
            sl[u] = same ? ~0u : (unsigned)ss[u] - clo;
            gp[u] = (dl[u] < CCH) ? ordArr[ss[u]] : 0u;
            gs[u] = (sl[u] < CCH) ? ordArr[dd[u]] : 0u;
        }
        // phase 3: LDS atomics (non-returning)
        #pragma unroll
        for (int u = 0; u < 16; ++u) {
            if (dl[u] < CCH) atomicMax(&preL[dl[u]], gp[u]);
            if (sl[u] < CCH) atomicMax(&sucL[sl[u]], gs[u]);
        }
    }
    for (int j = i; j < hi; ++j) {   // tail
        if (j >= lo) {
            int s = src[j], d = dst[j];
            if (s != d) {
                unsigned dl = (unsigned)d - clo;
                if (dl < CCH) atomicMax(&preL[dl], ordArr[s]);
                unsigned sl = (unsigned)s - clo;
                if (sl < CCH) atomicMax(&sucL[sl], ordArr[d]);
            }
        }
    }
    __syncthreads();
    size_t pb = ((size_t)c * split + sub) * CCH;
    size_t sucOff = (size_t)nch * split * CCH;
    for (int t = threadIdx.x; t < CCH; t += AT) {
        partials[pb + t] = preL[t];
        partials[sucOff + pb + t] = sucL[t];
    }
}

// ---- Fallback: device-scope filtered atomics (pre at [0], suc at [1<<17]) ----
__global__ void k_edges_dev(const int* __restrict__ src, const int* __restrict__ dst,
                            const float* __restrict__ h, unsigned* __restrict__ partials, int ne) {
    int e = blockIdx.x * blockDim.x + threadIdx.x;
    if (e >= ne) return;
    int s = src[e], d = dst[e];
    if (s == d) return;
    unsigned hs = f2ord(h[s]);
    unsigned hd = f2ord(h[d]);
    unsigned* slot0 = &partials[d];
    unsigned* slot1 = &partials[(1 << 17) + s];
    if (*slot0 < hs) atomicMax(slot0, hs);
    if (*slot1 < hd) atomicMax(slot1, hd);
}

// Fold split partials per direction; logit = h + w0*pre + w1*suc (0 -> 0.0);
// block-partial max (fixed RED_BLOCKS grid).
__global__ void k_logit_max(const float* __restrict__ h, const unsigned* __restrict__ partials,
                            const float* __restrict__ Wg, float* __restrict__ logit,
                            float* __restrict__ maxPart, int n, int nch, int split) {
    __shared__ float sm[256];
    float w0 = Wg[0], w1 = Wg[1];
    size_t sucOff = (size_t)nch * split * CCH;
    float m = -INFINITY;
    for (int i = blockIdx.x * 256 + threadIdx.x; i < n; i += 256 * RED_BLOCKS) {
        int c = i / CCH, loc = i - c * CCH;
        const unsigned* pp = partials + ((size_t)c * split) * CCH + loc;
        const unsigned* sp = pp + sucOff;
        unsigned p = 0, s = 0;
        #pragma unroll 4
        for (int k = 0; k < split; ++k) {
            p = max(p, pp[(size_t)k * CCH]);
            s = max(s, sp[(size_t)k * CCH]);
        }
        float pf = p ? ord2f(p) : 0.0f;
        float sf = s ? ord2f(s) : 0.0f;
        float l = h[i] + w0 * pf + w1 * sf;
        logit[i] = l;
        m = fmaxf(m, l);
    }
    sm[threadIdx.x] = m;
    __syncthreads();
    for (int off = 128; off > 0; off >>= 1) {
        if (threadIdx.x < off) sm[threadIdx.x] = fmaxf(sm[threadIdx.x], sm[threadIdx.x + off]);
        __syncthreads();
    }
    if (threadIdx.x == 0) maxPart[blockIdx.x] = sm[0];
}

// Fallback fold (flat pre/suc arrays).
__global__ void k_logit_max_dev(const float* __restrict__ h, const unsigned* __restrict__ partials,
                                const float* __restrict__ Wg, float* __restrict__ logit,
                                float* __restrict__ maxPart, int n) {
    __shared__ float sm[256];
    float w0 = Wg[0], w1 = Wg[1];
    float m = -INFINITY;
    for (int i = blockIdx.x * 256 + threadIdx.x; i < n; i += 256 * RED_BLOCKS) {
        unsigned p = partials[i], s = partials[(1 << 17) + i];
        float pf = p ? ord2f(p) : 0.0f;
        float sf = s ? ord2f(s) : 0.0f;
        float l = h[i] + w0 * pf + w1 * sf;
        logit[i] = l;
        m = fmaxf(m, l);
    }
    sm[threadIdx.x] = m;
    __syncthreads();
    for (int off = 128; off > 0; off >>= 1) {
        if (threadIdx.x < off) sm[threadIdx.x] = fmaxf(sm[threadIdx.x], sm[threadIdx.x + off]);
        __syncthreads();
    }
    if (threadIdx.x == 0) maxPart[blockIdx.x] = sm[0];
}

__global__ void k_exp_sum(const float* __restrict__ logit, const float* __restrict__ maxPart,
                          float* __restrict__ out, float* __restrict__ sumPart, int n) {
    __shared__ float sm[256];
    sm[threadIdx.x] = maxPart[threadIdx.x];
    __syncthreads();
    for (int off = 128; off > 0; off >>= 1) {
        if (threadIdx.x < off) sm[threadIdx.x] = fmaxf(sm[threadIdx.x], sm[threadIdx.x + off]);
        __syncthreads();
    }
    float gmax = sm[0];
    __syncthreads();
    float acc = 0.0f;
    for (int i = blockIdx.x * 256 + threadIdx.x; i < n; i += 256 * RED_BLOCKS) {
        float e = expf(logit[i] - gmax);
        out[i] = e;
        acc += e;
    }
    sm[threadIdx.x] = acc;
    __syncthreads();
    for (int off = 128; off > 0; off >>= 1) {
        if (threadIdx.x < off) sm[threadIdx.x] += sm[threadIdx.x + off];
        __syncthreads();
    }
    if (threadIdx.x == 0) sumPart[blockIdx.x] = sm[0];
}

__global__ void k_norm(const float* __restrict__ sumPart, float* __restrict__ out, int n) {
    __shared__ float sm[256];
    sm[threadIdx.x] = sumPart[threadIdx.x];
    __syncthreads();
    for (int off = 128; off > 0; off >>= 1) {
        if (threadIdx.x < off) sm[threadIdx.x] += sm[threadIdx.x + off];
        __syncthreads();
    }
    float inv = 1.0f / sm[0];
    for (int i = blockIdx.x * 256 + threadIdx.x; i < n; i += 256 * RED_BLOCKS) out[i] *= inv;
}

extern "C" void kernel_launch(void* const* d_in, const int* in_sizes, int n_in,
                              void* d_out, int out_size, void* d_ws, size_t ws_size,
                              hipStream_t stream) {
    const float* loss = (const float*)d_in[0];   // [N, 200]
    const float* Ws   = (const float*)d_in[1];   // [1, 200]
    const float* Wg   = (const float*)d_in[2];   // [1, 2]
    const int* esrc   = (const int*)d_in[3];     // [E]
    const int* edst   = (const int*)d_in[4];     // [E]
    float* out = (float*)d_out;                  // [N]

    const int n  = in_sizes[0] / 200;
    const int ne = in_sizes[3];
    const int Gh = (n + (NT / 16) - 1) / (NT / 16);

    const int nch = (n + CCH - 1) / CCH;                 // node chunks (7 @ n=100K)
    int split = 256 / nch; if (split < 1) split = 1;     // 1 block/CU, full residency
    const int epb = (((ne + split - 1) / split) + 15) & ~15;  // 16-aligned

    // ws layout (32-bit words):
    // h[n] | logit[n] | ordArr[n] | maxPart | sumPart | partials[2*nch*split*CCH]
    float*    h        = (float*)d_ws;
    float*    logit    = h + n;
    unsigned* ordArr   = (unsigned*)(logit + n);
    float*    maxPart  = (float*)(ordArr + n);
    float*    sumPart  = maxPart + RED_BLOCKS;
    unsigned* partials = (unsigned*)(sumPart + RED_BLOCKS);
    size_t part_w = (size_t)2 * nch * split * CCH;
    size_t need = ((size_t)3 * n + 2 * RED_BLOCKS + part_w) * 4;

    k_h<<<Gh, NT, 0, stream>>>(loss, Ws, h, ordArr, n);

    if (need <= ws_size) {
        k_accum<<<nch * split, AT, 0, stream>>>(esrc, edst, ordArr, partials, ne, nch, split, epb);
        k_logit_max<<<RED_BLOCKS, 256, 0, stream>>>(h, partials, Wg, logit, maxPart, n, nch, split);
    } else {
        hipMemsetAsync(partials, 0, (size_t)2 * (1 << 17) * 4, stream);
        k_edges_dev<<<(ne + 255) / 256, 256, 0, stream>>>(esrc, edst, h, partials, ne);
        k_logit_max_dev<<<RED_BLOCKS, 256, 0, stream>>>(h, partials, Wg, logit, maxPart, n);
    }

    k_exp_sum<<<RED_BLOCKS, 256, 0, stream>>>(logit, maxPart, out, sumPart, n);
    k_norm<<<RED_BLOCKS, 256, 0, stream>>>(sumPart, out, n);
}